// Round 1
// baseline (8053.738 us; speedup 1.0000x reference)
//
#include <hip/hip_runtime.h>
#include <stdint.h>

typedef unsigned short u16;
typedef unsigned int u32;
typedef __attribute__((ext_vector_type(8))) short bf16x8;
typedef __attribute__((ext_vector_type(4))) float f32x4;
typedef __attribute__((ext_vector_type(4))) u16 u16x4;

#define T_STEPS 256
#define BATCH 64
#define IDIM 1024
#define HDIM 1024
#define NBLK 256
#define NJ 4            // h-columns per block
#define KPAD 2056       // padded K stride (bf16 elems) for LDS W
#define THREADS 512
#define CNT_STRIDE 128  // u32 per barrier (8 slots x 16 u32 = 512 B)
#define NBAR 257
#define X_OFF 135168                                   // bytes into ws
#define H_OFF (X_OFF + T_STEPS * BATCH * IDIM * 2)     // bytes into ws
#define LDS_BYTES 83200                                 // 65792 (W) + 17408 (cand)

static __device__ __forceinline__ u16 f2bf(float f) {
  u32 u = __builtin_bit_cast(u32, f);
  u += 0x7FFFu + ((u >> 16) & 1u);
  return (u16)(u >> 16);
}
static __device__ __forceinline__ float sigf(float x) {
  return __builtin_amdgcn_rcpf(1.f + __expf(-x));
}
static __device__ __forceinline__ float tanhf_(float x) {
  float ax = __builtin_fabsf(x);
  float e = __expf(-2.f * ax);
  float t = 1.f - 2.f * e * __builtin_amdgcn_rcpf(1.f + e);
  return __builtin_copysignf(t, x);
}

// Grid barrier: 8 spread counters per barrier id, monotonic (zeroed by memset
// before launch). Release: syncthreads drains each thread's stores to L2
// (compiler emits s_waitcnt vmcnt(0) before s_barrier); thread0's
// __threadfence() does agent-scope L2 writeback. Acquire: pollers see full
// count, then __threadfence() invalidates L1/L2 before anyone reads h.
static __device__ __forceinline__ void gbar(u32* cnt, int bar, int bid, int tid) {
  __syncthreads();
  if (tid == 0) {
    __threadfence();
    __hip_atomic_fetch_add(&cnt[bar * CNT_STRIDE + (bid & 7) * 16], 1u,
                           __ATOMIC_RELEASE, __HIP_MEMORY_SCOPE_AGENT);
  }
  if (tid < 8) {
    while (__hip_atomic_load(&cnt[bar * CNT_STRIDE + tid * 16],
                             __ATOMIC_RELAXED, __HIP_MEMORY_SCOPE_AGENT) <
           (u32)(NBLK / 8)) {
      __builtin_amdgcn_s_sleep(1);
    }
    __threadfence();
  }
  __syncthreads();
}

__global__ __launch_bounds__(THREADS, 2)
void lstm_persistent(const float* __restrict__ x, const float* __restrict__ h0,
                     const float* __restrict__ c0, const float* __restrict__ W,
                     const float* __restrict__ bias, const int* __restrict__ L,
                     float* __restrict__ out, u16* __restrict__ xbf,
                     u16* __restrict__ hbuf, u32* __restrict__ cnt) {
  extern __shared__ char smem[];
  u16* Wlds = (u16*)smem;                 // [16 cols][KPAD] bf16 = 65792 B
  float* cand = (float*)(smem + 65792);   // [4 kq][64 b][17] f32 = 17408 B

  const int bid = blockIdx.x;
  const int tid = threadIdx.x;
  const int wave = tid >> 6;
  const int lane = tid & 63;
  const int q = lane >> 4;   // quad 0..3
  const int ln = lane & 15;
  const int mh = wave & 1;   // M half: rows [32*mh, 32*mh+32)
  const int kh = wave >> 1;  // K quarter: k in [kh*512, kh*512+512)

  // ---- phase 0a: x -> bf16 (grid-wide), h0 -> bf16 into hbuf[1] ----
  {
    const int gtid = bid * THREADS + tid;
    const f32x4* xv = (const f32x4*)x;
    u16x4* ov = (u16x4*)xbf;
#pragma unroll
    for (int it = 0; it < 32; ++it) {
      int i = gtid + it * (NBLK * THREADS);
      f32x4 v = xv[i];
      u16x4 o;
      o[0] = f2bf(v[0]); o[1] = f2bf(v[1]); o[2] = f2bf(v[2]); o[3] = f2bf(v[3]);
      ov[i] = o;
    }
    if (gtid < BATCH * HDIM) hbuf[BATCH * HDIM + gtid] = f2bf(h0[gtid]);
  }

  // ---- phase 0b: W slice -> LDS (bf16, column-major with K pad) ----
  // block owns global cols {g*1024 + bid*4 + j : g=0..3, j=0..3}; LDS col = g*4+j
  {
    const int g = tid & 3;
    const int kq2 = tid >> 2;  // 0..127
    const f32x4* Wv = (const f32x4*)W;  // one W row = 1024 f32x4
#pragma unroll 4
    for (int i = 0; i < 16; ++i) {
      int k = kq2 + 128 * i;
      f32x4 w4 = Wv[(size_t)k * 1024 + g * 256 + bid];
#pragma unroll
      for (int jj = 0; jj < 4; ++jj)
        Wlds[(g * 4 + jj) * KPAD + k] = f2bf(w4[jj]);
    }
  }

  // ---- per-thread pointwise state (threads 0..255: (b, j) pairs) ----
  float c_reg = 0.f, h_reg = 0.f, b_i = 0.f, b_f = 0.f, b_o = 0.f, b_g = 0.f;
  int Lb = 0, pb = 0, pj = 0;
  if (tid < 256) {
    pb = tid >> 2;
    pj = tid & 3;
    int gj = bid * NJ + pj;
    Lb = L[pb];
    c_reg = c0[pb * HDIM + gj];
    h_reg = h0[pb * HDIM + gj];
    b_i = bias[0 * HDIM + gj];
    b_f = bias[1 * HDIM + gj];
    b_o = bias[2 * HDIM + gj];
    b_g = bias[3 * HDIM + gj];
  }

  gbar(cnt, 0, bid, tid);  // x/h0 conversion complete everywhere

  const int arow = 32 * mh + ln;        // batch row of this wave's tile0
  const bool fromx = (kh < 2);
  const int kbase = (kh & 1) * 512;     // k offset within source (x or h)
  const u16* wp = &Wlds[ln * KPAD + kh * 512 + q * 8];

  for (int t = 0; t < T_STEPS; ++t) {
    const u16* Abase = fromx ? (xbf + (size_t)t * (BATCH * IDIM))
                             : (hbuf + ((t + 1) & 1) * (BATCH * HDIM));
    const u16* pa0 = Abase + arow * 1024 + kbase + q * 8;
    const u16* pa1 = pa0 + 16 * 1024;
    f32x4 acc0 = {0.f, 0.f, 0.f, 0.f};
    f32x4 acc1 = {0.f, 0.f, 0.f, 0.f};
#pragma unroll
    for (int ks = 0; ks < 16; ++ks) {
      bf16x8 a0 = *(const bf16x8*)(pa0 + ks * 32);
      bf16x8 a1 = *(const bf16x8*)(pa1 + ks * 32);
      bf16x8 bw = *(const bf16x8*)(wp + ks * 32);
      acc0 = __builtin_amdgcn_mfma_f32_16x16x32_bf16(a0, bw, acc0, 0, 0, 0);
      acc1 = __builtin_amdgcn_mfma_f32_16x16x32_bf16(a1, bw, acc1, 0, 0, 0);
    }
    // C/D layout: col = lane&15, row-in-tile = quad*4 + reg  (m89-verified)
    {
      float* c0p = &cand[(kh * 64 + 32 * mh + q * 4) * 17 + ln];
      float* c1p = c0p + 16 * 17;
#pragma unroll
      for (int r = 0; r < 4; ++r) {
        c0p[r * 17] = acc0[r];
        c1p[r * 17] = acc1[r];
      }
    }
    __syncthreads();
    if (tid < 256) {
      float vi = b_i, vf = b_f, vo = b_o, vg = b_g;
#pragma unroll
      for (int p = 0; p < 4; ++p) {
        const float* cp = &cand[(p * 64 + pb) * 17];
        vi += cp[pj];
        vf += cp[4 + pj];
        vo += cp[8 + pj];
        vg += cp[12 + pj];
      }
      float ig = sigf(vi), fg = sigf(vf), og = sigf(vo), gg = tanhf_(vg);
      float cn = ig * gg + fg * c_reg;
      float hn = og * tanhf_(cn);
      if (t < Lb) { c_reg = cn; h_reg = hn; }  // freeze past sequence end
      int gj = bid * NJ + pj;
      out[((size_t)t * BATCH + pb) * HDIM + gj] = h_reg;
      hbuf[(t & 1) * (BATCH * HDIM) + pb * HDIM + gj] = f2bf(h_reg);
    }
    gbar(cnt, 1 + t, bid, tid);  // h(t) published everywhere
  }
}

extern "C" void kernel_launch(void* const* d_in, const int* in_sizes, int n_in,
                              void* d_out, int out_size, void* d_ws, size_t ws_size,
                              hipStream_t stream) {
  (void)in_sizes; (void)n_in; (void)out_size; (void)ws_size;
  const float* x = (const float*)d_in[0];
  const float* h0 = (const float*)d_in[1];
  const float* c0 = (const float*)d_in[2];
  const float* W = (const float*)d_in[3];
  const float* bias = (const float*)d_in[4];
  const int* L = (const int*)d_in[5];
  float* out = (float*)d_out;

  char* ws = (char*)d_ws;
  u32* cnt = (u32*)ws;
  u16* xbf = (u16*)(ws + X_OFF);
  u16* hbuf = (u16*)(ws + H_OFF);

  hipFuncSetAttribute(reinterpret_cast<const void*>(lstm_persistent),
                      hipFuncAttributeMaxDynamicSharedMemorySize, 160 * 1024);
  hipMemsetAsync(cnt, 0, NBAR * CNT_STRIDE * 4, stream);
  hipLaunchKernelGGL(lstm_persistent, dim3(NBLK), dim3(THREADS), LDS_BYTES,
                     stream, x, h0, c0, W, bias, L, out, xbf, hbuf, cnt);
}

// Round 2
// 3440.763 us; speedup vs baseline: 2.3407x; 2.3407x over previous
//
#include <hip/hip_runtime.h>
#include <stdint.h>

typedef unsigned short u16;
typedef unsigned int u32;
typedef unsigned long long u64;
typedef __attribute__((ext_vector_type(8))) short bf16x8;
typedef __attribute__((ext_vector_type(4))) float f32x4;
typedef __attribute__((ext_vector_type(4))) u16 u16x4;
typedef __attribute__((ext_vector_type(2))) u64 u64x2;

#define T_STEPS 256
#define BATCH 64
#define IDIM 1024
#define HDIM 1024
#define NBLK 256
#define NJ 4            // h-columns per block
#define KPAD 2056       // padded K stride (bf16 elems) for LDS W
#define THREADS 512
#define CNT_STRIDE 128  // u32 per barrier (8 slots x 16 u32 = 512 B)
#define NBAR 257
#define GO_OFF 131584                                  // bytes: after cnt (257*512)
#define X_OFF 262144                                   // bytes into ws
#define H_OFF (X_OFF + T_STEPS * BATCH * IDIM * 2)     // bytes into ws
#define LDS_BYTES 83712  // 65792 (W) + 17408 (cand) + 512 (hstage)

static __device__ __forceinline__ u16 f2bf(float f) {
  u32 u = __builtin_bit_cast(u32, f);
  u += 0x7FFFu + ((u >> 16) & 1u);
  return (u16)(u >> 16);
}
static __device__ __forceinline__ float sigf(float x) {
  return __builtin_amdgcn_rcpf(1.f + __expf(-x));
}
static __device__ __forceinline__ float tanhf_(float x) {
  float ax = __builtin_fabsf(x);
  float e = __expf(-2.f * ax);
  float t = 1.f - 2.f * e * __builtin_amdgcn_rcpf(1.f + e);
  return __builtin_copysignf(t, x);
}

// ---- MCS-style grid barrier ----
// Arrive: fire-and-forget atomicAdd on 8 spread lines (32 adds each, nobody
// polls these but the watcher). Watcher (bid 0, tid<8) waits for 32 per line,
// then writes go[bar]. Everyone else: exactly ONE poller per block on the
// single-writer go line, with s_sleep backoff. No fences: all cross-block
// payload (h) moves via device-scope (sc1) accesses coherent at IF$; the
// pre-s_barrier vmcnt(0) drain orders h-stores before the arrive-add.
static __device__ __forceinline__ void gbar(u32* cnt, u32* go, int bar, int bid,
                                            int tid) {
  __syncthreads();  // drains all threads' stores (vmcnt(0) before s_barrier)
  if (tid == 0)
    __hip_atomic_fetch_add(&cnt[bar * CNT_STRIDE + (bid & 7) * 16], 1u,
                           __ATOMIC_RELAXED, __HIP_MEMORY_SCOPE_AGENT);
  if (bid == 0) {
    if (tid < 8) {
      while (__hip_atomic_load(&cnt[bar * CNT_STRIDE + tid * 16],
                               __ATOMIC_RELAXED, __HIP_MEMORY_SCOPE_AGENT) <
             (u32)(NBLK / 8))
        __builtin_amdgcn_s_sleep(1);
    }
    __syncthreads();
    if (tid == 0)
      __hip_atomic_store(&go[bar * 16], 1u, __ATOMIC_RELAXED,
                         __HIP_MEMORY_SCOPE_AGENT);
  } else {
    if (tid == 0) {
      while (__hip_atomic_load(&go[bar * 16], __ATOMIC_RELAXED,
                               __HIP_MEMORY_SCOPE_AGENT) == 0u)
        __builtin_amdgcn_s_sleep(4);
    }
  }
  __syncthreads();
}

// Heavy variant for barrier 0 only: xbf/h0 written with normal (cached)
// stores, so release needs wbl2 and acquire needs inv (threadfence).
static __device__ __forceinline__ void gbar_heavy(u32* cnt, u32* go, int bar,
                                                  int bid, int tid) {
  __syncthreads();
  if (tid == 0) {
    __threadfence();
    __hip_atomic_fetch_add(&cnt[bar * CNT_STRIDE + (bid & 7) * 16], 1u,
                           __ATOMIC_RELAXED, __HIP_MEMORY_SCOPE_AGENT);
  }
  if (bid == 0) {
    if (tid < 8) {
      while (__hip_atomic_load(&cnt[bar * CNT_STRIDE + tid * 16],
                               __ATOMIC_RELAXED, __HIP_MEMORY_SCOPE_AGENT) <
             (u32)(NBLK / 8))
        __builtin_amdgcn_s_sleep(1);
    }
    __syncthreads();
    if (tid == 0)
      __hip_atomic_store(&go[bar * 16], 1u, __ATOMIC_RELAXED,
                         __HIP_MEMORY_SCOPE_AGENT);
  } else {
    if (tid == 0) {
      while (__hip_atomic_load(&go[bar * 16], __ATOMIC_RELAXED,
                               __HIP_MEMORY_SCOPE_AGENT) == 0u)
        __builtin_amdgcn_s_sleep(4);
    }
  }
  if (tid == 0) __threadfence();  // acquire: invalidate L1/L2 before reads
  __syncthreads();
}

__global__ __launch_bounds__(THREADS, 2)
void lstm_persistent(const float* __restrict__ x, const float* __restrict__ h0,
                     const float* __restrict__ c0, const float* __restrict__ W,
                     const float* __restrict__ bias, const int* __restrict__ L,
                     float* __restrict__ out, u16* __restrict__ xbf,
                     u16* __restrict__ hbuf, u32* __restrict__ cnt,
                     u32* __restrict__ go) {
  extern __shared__ char smem[];
  u16* Wlds = (u16*)smem;                 // [16 cols][KPAD] bf16 = 65792 B
  float* cand = (float*)(smem + 65792);   // [4 kq][64 b][17] f32 = 17408 B
  u16* hstage = (u16*)(smem + 83200);     // [256] bf16 staging = 512 B

  const int bid = blockIdx.x;
  const int tid = threadIdx.x;
  const int wave = tid >> 6;
  const int lane = tid & 63;
  const int q = lane >> 4;   // quad 0..3
  const int ln = lane & 15;
  const int mh = wave & 1;   // M half: rows [32*mh, 32*mh+32)
  const int kh = wave >> 1;  // K quarter: k in [kh*512, kh*512+512)

  // ---- phase 0a: x -> bf16 (grid-wide), h0 -> bf16 into hbuf[1] ----
  {
    const int gtid = bid * THREADS + tid;
    const f32x4* xv = (const f32x4*)x;
    u16x4* ov = (u16x4*)xbf;
#pragma unroll
    for (int it = 0; it < 32; ++it) {
      int i = gtid + it * (NBLK * THREADS);
      f32x4 v = xv[i];
      u16x4 o;
      o[0] = f2bf(v[0]); o[1] = f2bf(v[1]); o[2] = f2bf(v[2]); o[3] = f2bf(v[3]);
      ov[i] = o;
    }
    if (gtid < BATCH * HDIM) hbuf[BATCH * HDIM + gtid] = f2bf(h0[gtid]);
  }

  // ---- phase 0b: W slice -> LDS (bf16, column-major with K pad) ----
  {
    const int g = tid & 3;
    const int kq2 = tid >> 2;  // 0..127
    const f32x4* Wv = (const f32x4*)W;  // one W row = 1024 f32x4
#pragma unroll 4
    for (int i = 0; i < 16; ++i) {
      int k = kq2 + 128 * i;
      f32x4 w4 = Wv[(size_t)k * 1024 + g * 256 + bid];
#pragma unroll
      for (int jj = 0; jj < 4; ++jj)
        Wlds[(g * 4 + jj) * KPAD + k] = f2bf(w4[jj]);
    }
  }

  // ---- per-thread pointwise state (threads 0..255: (b, j) pairs) ----
  float c_reg = 0.f, h_reg = 0.f, b_i = 0.f, b_f = 0.f, b_o = 0.f, b_g = 0.f;
  int Lb = 0, pb = 0, pj = 0;
  if (tid < 256) {
    pb = tid >> 2;
    pj = tid & 3;
    int gj = bid * NJ + pj;
    Lb = L[pb];
    c_reg = c0[pb * HDIM + gj];
    h_reg = h0[pb * HDIM + gj];
    b_i = bias[0 * HDIM + gj];
    b_f = bias[1 * HDIM + gj];
    b_o = bias[2 * HDIM + gj];
    b_g = bias[3 * HDIM + gj];
  }

  gbar_heavy(cnt, go, 0, bid, tid);  // x/h0 conversion visible everywhere

  const int arow = 32 * mh + ln;        // batch row of this wave's tile0
  const bool fromx = (kh < 2);
  const int kbase = (kh & 1) * 512;     // k offset within source (x or h)
  const u16* wp = &Wlds[ln * KPAD + kh * 512 + q * 8];

  for (int t = 0; t < T_STEPS; ++t) {
    f32x4 acc0 = {0.f, 0.f, 0.f, 0.f};
    f32x4 acc1 = {0.f, 0.f, 0.f, 0.f};
    if (fromx) {
      // x-half: normal cached loads (x immutable; stays hot in local L2)
      const u16* pa0 =
          xbf + (size_t)t * (BATCH * IDIM) + arow * 1024 + kbase + q * 8;
      const u16* pa1 = pa0 + 16 * 1024;
#pragma unroll
      for (int ks = 0; ks < 16; ++ks) {
        bf16x8 a0 = *(const bf16x8*)(pa0 + ks * 32);
        bf16x8 a1 = *(const bf16x8*)(pa1 + ks * 32);
        bf16x8 bw = *(const bf16x8*)(wp + ks * 32);
        acc0 = __builtin_amdgcn_mfma_f32_16x16x32_bf16(a0, bw, acc0, 0, 0, 0);
        acc1 = __builtin_amdgcn_mfma_f32_16x16x32_bf16(a1, bw, acc1, 0, 0, 0);
      }
    } else {
      // h-half: device-scope (sc1) loads — coherent at IF$, no fences needed
      const u16* pa0 = hbuf + ((t + 1) & 1) * (BATCH * HDIM) + arow * 1024 +
                       kbase + q * 8;
      const u16* pa1 = pa0 + 16 * 1024;
#pragma unroll
      for (int ks = 0; ks < 16; ++ks) {
        u64x2 r0, r1;
        r0[0] = __hip_atomic_load((const u64*)(pa0 + ks * 32), __ATOMIC_RELAXED,
                                  __HIP_MEMORY_SCOPE_AGENT);
        r0[1] = __hip_atomic_load((const u64*)(pa0 + ks * 32 + 4),
                                  __ATOMIC_RELAXED, __HIP_MEMORY_SCOPE_AGENT);
        r1[0] = __hip_atomic_load((const u64*)(pa1 + ks * 32), __ATOMIC_RELAXED,
                                  __HIP_MEMORY_SCOPE_AGENT);
        r1[1] = __hip_atomic_load((const u64*)(pa1 + ks * 32 + 4),
                                  __ATOMIC_RELAXED, __HIP_MEMORY_SCOPE_AGENT);
        bf16x8 a0 = __builtin_bit_cast(bf16x8, r0);
        bf16x8 a1 = __builtin_bit_cast(bf16x8, r1);
        bf16x8 bw = *(const bf16x8*)(wp + ks * 32);
        acc0 = __builtin_amdgcn_mfma_f32_16x16x32_bf16(a0, bw, acc0, 0, 0, 0);
        acc1 = __builtin_amdgcn_mfma_f32_16x16x32_bf16(a1, bw, acc1, 0, 0, 0);
      }
    }
    // C/D layout: col = lane&15, row-in-tile = quad*4 + reg  (m89-verified)
    {
      float* c0p = &cand[(kh * 64 + 32 * mh + q * 4) * 17 + ln];
      float* c1p = c0p + 16 * 17;
#pragma unroll
      for (int r = 0; r < 4; ++r) {
        c0p[r * 17] = acc0[r];
        c1p[r * 17] = acc1[r];
      }
    }
    __syncthreads();
    if (tid < 256) {
      float vi = b_i, vf = b_f, vo = b_o, vg = b_g;
#pragma unroll
      for (int p = 0; p < 4; ++p) {
        const float* cp = &cand[(p * 64 + pb) * 17];
        vi += cp[pj];
        vf += cp[4 + pj];
        vo += cp[8 + pj];
        vg += cp[12 + pj];
      }
      float ig = sigf(vi), fg = sigf(vf), og = sigf(vo), gg = tanhf_(vg);
      float cn = ig * gg + fg * c_reg;
      float hn = og * tanhf_(cn);
      if (t < Lb) { c_reg = cn; h_reg = hn; }  // freeze past sequence end
      out[((size_t)t * BATCH + pb) * HDIM + bid * NJ + pj] = h_reg;
      hstage[tid] = f2bf(h_reg);
    }
    __syncthreads();
    if (tid < 64) {
      // publish h: device-scope u64 stores (4 bf16 each), write-through to IF$
      u64 v = ((const u64*)hstage)[tid];
      u64* dst = (u64*)(hbuf + (t & 1) * (BATCH * HDIM) + tid * HDIM + bid * NJ);
      __hip_atomic_store(dst, v, __ATOMIC_RELAXED, __HIP_MEMORY_SCOPE_AGENT);
    }
    gbar(cnt, go, 1 + t, bid, tid);  // h(t) at IF$ before add (vmcnt drain)
  }
}

extern "C" void kernel_launch(void* const* d_in, const int* in_sizes, int n_in,
                              void* d_out, int out_size, void* d_ws, size_t ws_size,
                              hipStream_t stream) {
  (void)in_sizes; (void)n_in; (void)out_size; (void)ws_size;
  const float* x = (const float*)d_in[0];
  const float* h0 = (const float*)d_in[1];
  const float* c0 = (const float*)d_in[2];
  const float* W = (const float*)d_in[3];
  const float* bias = (const float*)d_in[4];
  const int* L = (const int*)d_in[5];
  float* out = (float*)d_out;

  char* ws = (char*)d_ws;
  u32* cnt = (u32*)ws;
  u32* go = (u32*)(ws + GO_OFF);
  u16* xbf = (u16*)(ws + X_OFF);
  u16* hbuf = (u16*)(ws + H_OFF);

  hipFuncSetAttribute(reinterpret_cast<const void*>(lstm_persistent),
                      hipFuncAttributeMaxDynamicSharedMemorySize, 160 * 1024);
  hipMemsetAsync(ws, 0, X_OFF, stream);  // zero cnt + go
  hipLaunchKernelGGL(lstm_persistent, dim3(NBLK), dim3(THREADS), LDS_BYTES,
                     stream, x, h0, c0, W, bias, L, out, xbf, hbuf, cnt, go);
}